// Round 1
// 375.922 us; speedup vs baseline: 1.0080x; 1.0080x over previous
//
#include <hip/hip_runtime.h>
#include <math.h>

// ConvTranspose2d(64,64,k4,s2,p1) + bias + mish + 0.5 clamp[-1,1] *2, via MFMA.
// Quadrant decomposition: output parity (r,s) -> 2x2 stride-1 conv.
// GEMM per (n,y,quadrant): M=64 oc, N=64 x-pos, K=256=(j,kk)x64ic.
// v4: LDS-staged coalesced epilogue (float4 stores, 2x16KB dbuf, XOR-swizzled
// conflict-free staging), bias folded to reader side, prefetch moved post-MFMA
// to cut register liveness below the 256-VGPR cap.

typedef __attribute__((ext_vector_type(8))) short bf16x8;
typedef __attribute__((ext_vector_type(4))) float floatx4;

#define LDS_ROW 4224    // 66 cols * 64 ic (ushort units)
#define RING_USH 16896  // 4 slots * 4224
#define OST_DW 4096     // dwords per ostage buffer (16 KB)

__device__ __forceinline__ unsigned short f2bf(float f) {
    unsigned int u = __float_as_uint(f);
    u += 0x7fffu + ((u >> 16) & 1u);
    return (unsigned short)(u >> 16);
}

__device__ __forceinline__ unsigned long long pack4(unsigned short a, unsigned short b,
                                                    unsigned short c, unsigned short d) {
    return (unsigned long long)a | ((unsigned long long)b << 16) |
           ((unsigned long long)c << 32) | ((unsigned long long)d << 48);
}

__device__ __forceinline__ float act(float y) {
    // mish(y) = y*tanh(softplus(y)); tanh(ln(1+e)) = (e^2+2e)/(e^2+2e+2)
    // lower clamp never binds (mish+0.5 >= 0.19); y>8 saturates upper clamp.
    float t = fminf(y, 8.f);
    float e = __expf(t);
    float p = e * (e + 2.f);
    float m = t * p * __builtin_amdgcn_rcpf(p + 2.f);
    float v = fminf(m + 0.5f, 1.f);
    return v + v;
}

__global__ __launch_bounds__(256, 2) void convt_mfma4(
    const float* __restrict__ x, const float* __restrict__ w,
    const float* __restrict__ bias, float* __restrict__ out)
{
    // ring (33792 B) + 2x16KB output staging = 66560 B total
    __shared__ __align__(16) unsigned short lds[RING_USH + 2 * OST_DW * 2];

    const int tid  = threadIdx.x;
    const int lane = tid & 63;
    const int wid  = tid >> 6;
    const int r = wid >> 1, s = wid & 1;        // quadrant
    const int q = lane >> 4, mcol = lane & 15;  // MFMA lane decomposition

    const int bid = blockIdx.x;
    const int n   = bid >> 3;
    const int y0  = (bid & 7) * 8;

    const float* xn = x + (size_t)n * 262144;   // 64*64*64

    // ---------------- stage weights -> persistent A fragments ----------------
    bf16x8 a[4][8];
    {
        const int tap = tid & 15;
        const int icq = tid >> 4;
        const int icw = icq * 4;
        for (int c = 0; c < 4; ++c) {
            __syncthreads();
            #pragma unroll
            for (int it = 0; it < 16; ++it) {
                const float* wp = w + ((16 * c + it) * 1024 + icw * 16 + tap);
                unsigned long long pk = pack4(f2bf(wp[0]), f2bf(wp[16]),
                                              f2bf(wp[32]), f2bf(wp[48]));
                *(unsigned long long*)&lds[(it * 16 + tap) * 64 + (icw ^ ((tap & 7) * 8))] = pk;
            }
            __syncthreads();
            #pragma unroll
            for (int ks = 0; ks < 8; ++ks) {
                const int tl = ks >> 1;
                const int j = tl >> 1, kk = tl & 1;
                const int kh = 3 - r - 2 * j, kw = 3 - s - 2 * kk;
                const int tapidx = kh * 4 + kw;
                const int ic0 = (ks & 1) * 32 + q * 8;
                a[c][ks] = *(const bf16x8*)&lds[(mcol * 16 + tapidx) * 64 +
                                                (ic0 ^ ((tapidx & 7) * 8))];
            }
        }
    }

    // reader-side decomposition for the staged epilogue:
    //   reader r  = wid>>1 (same as writer r)
    //   cc        = s*4+q   (oc'-pair index, 0..7)  -> oc' = 2cc, 2cc+1
    //   w         = mcol + 16k (k=0,1)              -> ow = 4w..4w+3
    const int cc = s * 4 + q;

    float biasA[4], biasB[4];
    #pragma unroll
    for (int mt = 0; mt < 4; ++mt) {
        biasA[mt] = bias[mt * 16 + 2 * cc];
        biasB[mt] = bias[mt * 16 + 2 * cc + 1];
    }

    __syncthreads();   // a-frag reads done; lds becomes the x row ring

    // staging thread mapping: 4 cols x 4 ic per thread
    const int colg = tid & 15, icg = tid >> 4;
    const int c0 = colg * 4, ic0s = icg * 4;

    auto write_row = [&](int slot, const float4& v0, const float4& v1,
                         const float4& v2, const float4& v3) {
        #pragma unroll
        for (int k = 0; k < 4; ++k) {
            const int cp = c0 + k + 1;
            unsigned long long pk = pack4(f2bf((&v0.x)[k]), f2bf((&v1.x)[k]),
                                          f2bf((&v2.x)[k]), f2bf((&v3.x)[k]));
            *(unsigned long long*)&lds[slot * LDS_ROW + cp * 64 +
                                       (ic0s ^ ((cp & 7) * 8))] = pk;
        }
    };
    auto load_row = [&](int ry, float4& v0, float4& v1, float4& v2, float4& v3) {
        const float* xp = xn + (size_t)ic0s * 4096 + ry * 64 + c0;
        v0 = *(const float4*)(xp);
        v1 = *(const float4*)(xp + 4096);
        v2 = *(const float4*)(xp + 8192);
        v3 = *(const float4*)(xp + 12288);
    };
    const float4 z4 = {0.f, 0.f, 0.f, 0.f};

    // ostage writer: raw acc values for chunk mt into buffer buf.
    // layout (dwords): [s][r][x 0..63][oc' 0..15] with oc'-nibble swizzle q^(x&3)
    auto stage_write = [&](const floatx4 (&am)[4], int buf) {
        float* ob = (float*)&lds[RING_USH] + buf * OST_DW + (s * 2 + r) * 1024;
        #pragma unroll
        for (int nt = 0; nt < 4; ++nt) {
            const int xx = nt * 16 + mcol;
            *(floatx4*)&ob[xx * 16 + ((q ^ (xx & 3)) * 4)] = am[nt];
        }
    };

    // ostage reader: bias + act + coalesced float4 stores
    auto stage_store = [&](int mt, int buf, int y) {
        const float* ob = (const float*)&lds[RING_USH] + buf * OST_DW;
        const int plane0 = r * 64;         // s=0 plane (in x-rows)
        const int plane1 = (2 + r) * 64;   // s=1 plane
        const int qo = cc >> 1, lp = (cc & 1) * 2;
        const int oc0 = mt * 16 + 2 * cc;
        #pragma unroll
        for (int k = 0; k < 2; ++k) {
            const int ww = mcol + 16 * k;
            const int x0 = 2 * ww, x1 = x0 + 1;
            const float2 e00 = *(const float2*)&ob[(plane0 + x0) * 16 + ((qo ^ (x0 & 3)) * 4) + lp];
            const float2 e10 = *(const float2*)&ob[(plane1 + x0) * 16 + ((qo ^ (x0 & 3)) * 4) + lp];
            const float2 e01 = *(const float2*)&ob[(plane0 + x1) * 16 + ((qo ^ (x1 & 3)) * 4) + lp];
            const float2 e11 = *(const float2*)&ob[(plane1 + x1) * 16 + ((qo ^ (x1 & 3)) * 4) + lp];
            const int oh = 2 * y + r;
            float4 o0, o1;
            o0.x = act(e00.x + biasA[mt]); o0.y = act(e10.x + biasA[mt]);
            o0.z = act(e01.x + biasA[mt]); o0.w = act(e11.x + biasA[mt]);
            o1.x = act(e00.y + biasB[mt]); o1.y = act(e10.y + biasB[mt]);
            o1.z = act(e01.y + biasB[mt]); o1.w = act(e11.y + biasB[mt]);
            *(float4*)&out[(((size_t)n * 64 + oc0) * 128 + oh) * 128 + 4 * ww] = o0;
            *(float4*)&out[(((size_t)n * 64 + oc0 + 1) * 128 + oh) * 128 + 4 * ww] = o1;
        }
    };

    // halo cols (cp=0,65) are zero for every row: zero once, all 4 slots
    if (tid < 64) {
        const int slot = tid >> 4;
        const int cpz  = ((tid >> 3) & 1) ? 65 : 0;
        const int part = tid & 7;   // 8 ushorts each
        unsigned long long* p =
            (unsigned long long*)&lds[slot * LDS_ROW + cpz * 64 + part * 8];
        p[0] = 0ULL; p[1] = 0ULL;
    }

    // prologue: rows y0-1, y0, y0+1 -> slots 0,1,2
    #pragma unroll
    for (int pr = 0; pr < 3; ++pr) {
        const int ry = y0 - 1 + pr;
        float4 v0 = z4, v1 = z4, v2 = z4, v3 = z4;
        if (ry >= 0 && ry < 64) load_row(ry, v0, v1, v2, v3);
        write_row(pr, v0, v1, v2, v3);
    }

    for (int iy = 0; iy < 8; ++iy) {
        const int y = y0 + iy;
        __syncthreads();   // ring writes visible; prev iter's ostage reads done

        // ---- MFMA compute for output row pair at y ----
        floatx4 acc[4][4];
        #pragma unroll
        for (int mt = 0; mt < 4; ++mt)
            #pragma unroll
            for (int nt = 0; nt < 4; ++nt)
                acc[mt][nt] = (floatx4){0.f, 0.f, 0.f, 0.f};

        #pragma unroll
        for (int ks = 0; ks < 8; ++ks) {
            const int tl = ks >> 1;
            const int j = tl >> 1, kk = tl & 1;
            const int slotj = (iy + r + j) & 3;         // row y-1+r+j
            const int icb = (ks & 1) * 32 + q * 8;
            bf16x8 b[4];
            #pragma unroll
            for (int nt = 0; nt < 4; ++nt) {
                const int cp = nt * 16 + mcol + kk + s;
                b[nt] = *(const bf16x8*)&lds[slotj * LDS_ROW + cp * 64 +
                                             (icb ^ ((cp & 7) * 8))];
            }
            #pragma unroll
            for (int mt = 0; mt < 4; ++mt)
                #pragma unroll
                for (int nt = 0; nt < 4; ++nt)
                    acc[mt][nt] = __builtin_amdgcn_mfma_f32_16x16x32_bf16(
                        a[mt][ks], b[nt], acc[mt][nt], 0, 0, 0);
        }

        // prefetch next row into regs (consumed at phase mt==3; ~4 phases of
        // staging/stores between issue and use hide the HBM latency)
        const int ry_pf = y + 2;
        const bool pf_valid = (iy < 7) && (ry_pf < 64);
        float4 p0 = z4, p1 = z4, p2 = z4, p3 = z4;
        if (pf_valid) load_row(ry_pf, p0, p1, p2, p3);

        // ---- staged epilogue: 4 mt-chunks, double-buffered ----
        stage_write(acc[0], 0);
        #pragma unroll
        for (int mt = 0; mt < 4; ++mt) {
            __syncthreads();
            if (mt < 3) stage_write(acc[mt + 1], (mt + 1) & 1);
            else if (iy < 7) write_row((iy + 3) & 3, p0, p1, p2, p3);
            stage_store(mt, mt & 1, y);
        }
    }
}

extern "C" void kernel_launch(void* const* d_in, const int* in_sizes, int n_in,
                              void* d_out, int out_size, void* d_ws, size_t ws_size,
                              hipStream_t stream) {
    const float* x    = (const float*)d_in[0];
    const float* wgt  = (const float*)d_in[1];
    const float* bias = (const float*)d_in[2];
    float* out = (float*)d_out;

    convt_mfma4<<<dim3(512), dim3(256), 0, stream>>>(x, wgt, bias, out);
}